// Round 2
// baseline (414.401 us; speedup 1.0000x reference)
//
#include <hip/hip_runtime.h>
#include <stdint.h>

#define T_DIM 8192
#define K_DIM 4096
#define N_DIM 4096
#define FP8MAX 448.0f
#define NT     32        // K tiles of 128 elements (= 128 B fp8)
#define BUFB   49152     // per-K-tile LDS buffer: A 256x128 B (32K) + B 128x128 B (16K)

typedef __attribute__((ext_vector_type(4))) float floatx4;
typedef __attribute__((ext_vector_type(4))) int   intx4;
typedef __attribute__((ext_vector_type(8))) int   intx8;

// ---------- helpers ----------

__device__ static inline void load16_g2lds(const void* gptr, void* lptr) {
    __builtin_amdgcn_global_load_lds(
        (const __attribute__((address_space(1))) void*)gptr,
        (__attribute__((address_space(3))) void*)lptr,
        16, 0, 0);
}

// pack 4 floats -> 4 fp8 e4m3fn bytes (HW RNE cvt; OCP format on gfx950)
__device__ static inline uint32_t pack4_fp8(float f0, float f1, float f2, float f3) {
    int p = 0;
    p = __builtin_amdgcn_cvt_pk_fp8_f32(f0, f1, p, false); // bytes 0,1
    p = __builtin_amdgcn_cvt_pk_fp8_f32(f2, f3, p, true);  // bytes 2,3
    return (uint32_t)p;
}

// ---------- kernel 1: fused quantization (unchanged from verified version) ----------
__global__ __launch_bounds__(256) void quant_fused_kernel(
    const float* __restrict__ x, const float* __restrict__ w,
    uint8_t* __restrict__ xq, uint8_t* __restrict__ wqT,
    float* __restrict__ xscale)
{
    const int tid = threadIdx.x;
    if (blockIdx.x < T_DIM) {
        const int t = blockIdx.x;
        const int lane = tid & 63;
        const int wave = tid >> 6;
        const float4* xr4 = (const float4*)(x + (size_t)t * K_DIM);

        float4 v[4];
        float m = 0.0f;
#pragma unroll
        for (int e = 0; e < 4; ++e) {
            v[e] = xr4[tid + e * 256];
            m = fmaxf(m, fmaxf(fmaxf(fabsf(v[e].x), fabsf(v[e].y)),
                               fmaxf(fabsf(v[e].z), fabsf(v[e].w))));
        }
#pragma unroll
        for (int off = 32; off > 0; off >>= 1)
            m = fmaxf(m, __shfl_down(m, off, 64));
        __shared__ float red[4];
        if (lane == 0) red[wave] = m;
        __syncthreads();
        float mm = fmaxf(fmaxf(red[0], red[1]), fmaxf(red[2], red[3]));
        float scale = fmaxf(mm / FP8MAX, 1e-12f);
        if (tid == 0) xscale[t] = scale;
        const float inv = 1.0f / scale;

        uint32_t* xqr = (uint32_t*)(xq + (size_t)t * K_DIM);
#pragma unroll
        for (int e = 0; e < 4; ++e) {
            float q0 = fminf(fmaxf(v[e].x * inv, -FP8MAX), FP8MAX);
            float q1 = fminf(fmaxf(v[e].y * inv, -FP8MAX), FP8MAX);
            float q2 = fminf(fmaxf(v[e].z * inv, -FP8MAX), FP8MAX);
            float q3 = fminf(fmaxf(v[e].w * inv, -FP8MAX), FP8MAX);
            xqr[tid + e * 256] = pack4_fp8(q0, q1, q2, q3);
        }
    } else {
        const int b = blockIdx.x - T_DIM;
        const int n0 = (b & 63) * 64;
        const int k0 = (b >> 6) * 64;
        __shared__ uint32_t tile[64][17];

#pragma unroll
        for (int e = 0; e < 4; ++e) {
            int idx = tid + e * 256;
            int r = idx >> 4;
            int c4 = idx & 15;
            float4 v = *(const float4*)(w + (size_t)(k0 + r) * N_DIM + n0 + c4 * 4);
            tile[r][c4] = pack4_fp8(v.x, v.y, v.z, v.w);
        }
        __syncthreads();
        const int kg = tid & 15;
        const int ng = tid >> 4;
        uint32_t in0 = tile[kg * 4 + 0][ng];
        uint32_t in1 = tile[kg * 4 + 1][ng];
        uint32_t in2 = tile[kg * 4 + 2][ng];
        uint32_t in3 = tile[kg * 4 + 3][ng];
#pragma unroll
        for (int i = 0; i < 4; ++i) {
            uint32_t o = ((in0 >> (8 * i)) & 0xFFu)
                       | (((in1 >> (8 * i)) & 0xFFu) << 8)
                       | (((in2 >> (8 * i)) & 0xFFu) << 16)
                       | (((in3 >> (8 * i)) & 0xFFu) << 24);
            *(uint32_t*)(wqT + (size_t)(n0 + ng * 4 + i) * K_DIM + k0 + kg * 4) = o;
        }
    }
}

// ---------- kernel 2: fp8 GEMM, counted-vmcnt deep pipeline ----------
// 256x128 tile, BK=128B, 8 waves (4M x 2N, 64x64 each), triple-buffered LDS.
// Pipeline: stage tile t+2 while computing tile t; loop-top gate is
// s_waitcnt vmcnt(6) (tile t landed, tile t+1's 6 loads stay in flight) —
// vmcnt never drains to 0 in the main loop (T3+T4). Raw s_barrier (no
// waitcnt drain), 4 phases/K-tile of {ds_read || stage-issue -> barrier ->
// setprio(1) 4x MFMA setprio(0) -> barrier} (T5). LDS XOR-16B swizzle:
// slot gg = g ^ (row&7), cancelled on read. Hazards: stage of tile t+2
// writes buf[(t+2)%3] = buffer whose reads finished in iter t-1 (WAR fenced
// by loop-top barrier); in-flight DMA never targets the buffer being read.
__global__ __launch_bounds__(512, 2) void gemm_fp8_kernel(
    const uint8_t* __restrict__ xq, const uint8_t* __restrict__ wqT,
    const float* __restrict__ xscale, const float* __restrict__ wscale,
    float* __restrict__ out)
{
    __shared__ __align__(16) uint8_t lds[3 * BUFB]; // 144 KB -> 1 block/CU, 2 waves/SIMD

    const int tid  = threadIdx.x;   // 0..511
    const int lane = tid & 63;
    const int wave = tid >> 6;      // 0..7

    // XCD-bijective block swizzle: nwg=1024, 8 XCDs, 128 contiguous tiles each
    const int bid = blockIdx.y * gridDim.x + blockIdx.x;
    const int swz = (bid & 7) * 128 + (bid >> 3);
    const int m0 = (swz >> 5) * 256;  // 32 M-tiles
    const int n0 = (swz & 31) * 128;  // 32 N-tiles

    const int wm = (wave >> 1) * 64;  // 0,64,128,192
    const int wn = (wave & 1) * 64;   // 0,64
    const int row  = lane & 15;
    const int quad = lane >> 4;

    floatx4 acc[4][4] = {{{0.f,0.f,0.f,0.f}}};

    // ---- staging addresses (6 x 16B loads per thread per K-tile: A0..A3,B0,B1) ----
    const uint8_t* gA[4]; uint32_t lA[4];
    const uint8_t* gB[2]; uint32_t lB[2];
#pragma unroll
    for (int p = 0; p < 4; ++p) {
        const int c = tid + p * 512;               // 0..2047 (256 rows x 8 groups)
        const int r = c >> 3, gg = c & 7, g = gg ^ (r & 7);
        gA[p] = xq + (size_t)(m0 + r) * K_DIM + g * 16;
        lA[p] = (uint32_t)c * 16u;
    }
#pragma unroll
    for (int p = 0; p < 2; ++p) {
        const int c = tid + p * 512;               // 0..1023 (128 rows x 8 groups)
        const int r = c >> 3, gg = c & 7, g = gg ^ (r & 7);
        gB[p] = wqT + (size_t)(n0 + r) * K_DIM + g * 16;
        lB[p] = 32768u + (uint32_t)c * 16u;
    }

    // ---- fragment read offsets (relative to buffer base; swizzle cancels) ----
    int aoff0[4], aoff1[4], boff0[4], boff1[4];
#pragma unroll
    for (int i = 0; i < 4; ++i) {
        const int mr = wm + i * 16 + row;          // 0..255
        const int nr = wn + i * 16 + row;          // 0..127
        aoff0[i] = mr * 128 + (((2 * quad)     ^ (mr & 7)) << 4);
        aoff1[i] = mr * 128 + (((2 * quad + 1) ^ (mr & 7)) << 4);
        boff0[i] = 32768 + nr * 128 + (((2 * quad)     ^ (nr & 7)) << 4);
        boff1[i] = 32768 + nr * 128 + (((2 * quad + 1) ^ (nr & 7)) << 4);
    }

#define READ_A(i) { \
    intx4 lo = *(const intx4*)(Ab + aoff0[i]); \
    intx4 hi = *(const intx4*)(Ab + aoff1[i]); \
    a[i] = __builtin_shufflevector(lo, hi, 0, 1, 2, 3, 4, 5, 6, 7); }
#define READ_B(j) { \
    intx4 lo = *(const intx4*)(Ab + boff0[j]); \
    intx4 hi = *(const intx4*)(Ab + boff1[j]); \
    b[j] = __builtin_shufflevector(lo, hi, 0, 1, 2, 3, 4, 5, 6, 7); }
#define MFMA_ROW(i) \
    acc[i][0] = __builtin_amdgcn_mfma_scale_f32_16x16x128_f8f6f4(a[i], b[0], acc[i][0], 0, 0, 0, 0x7F7F7F7F, 0, 0x7F7F7F7F); \
    acc[i][1] = __builtin_amdgcn_mfma_scale_f32_16x16x128_f8f6f4(a[i], b[1], acc[i][1], 0, 0, 0, 0x7F7F7F7F, 0, 0x7F7F7F7F); \
    acc[i][2] = __builtin_amdgcn_mfma_scale_f32_16x16x128_f8f6f4(a[i], b[2], acc[i][2], 0, 0, 0, 0x7F7F7F7F, 0, 0x7F7F7F7F); \
    acc[i][3] = __builtin_amdgcn_mfma_scale_f32_16x16x128_f8f6f4(a[i], b[3], acc[i][3], 0, 0, 0, 0x7F7F7F7F, 0, 0x7F7F7F7F);

    // ---- prologue: prefetch tile 0 -> buf0, tile 1 -> buf1 (12 loads in flight) ----
#pragma unroll
    for (int p = 0; p < 4; ++p) load16_g2lds(gA[p], &lds[lA[p]]);
#pragma unroll
    for (int p = 0; p < 2; ++p) load16_g2lds(gB[p], &lds[lB[p]]);
#pragma unroll
    for (int p = 0; p < 4; ++p) load16_g2lds(gA[p] + 128, &lds[BUFB + lA[p]]);
#pragma unroll
    for (int p = 0; p < 2; ++p) load16_g2lds(gB[p] + 128, &lds[BUFB + lB[p]]);

    int rd = 0;
    for (int t = 0; t < NT - 1; ++t) {
        // counted gate: tile t's 6 loads landed; tile t+1's 6 stay in flight
        asm volatile("s_waitcnt vmcnt(6)" ::: "memory");
        __builtin_amdgcn_s_barrier();
        asm volatile("" ::: "memory"); // keep ds_reads below the gate

        const uint8_t* Ab = &lds[(uint32_t)rd * BUFB];
        int st = rd + 2; if (st >= 3) st -= 3;
        const uint32_t sb = (uint32_t)st * BUFB;
        const int kk = (t + 2) * 128;
        const bool stg = (t < NT - 2);

        intx8 a[4], b[4];
        // phase 0: all B frags + A row 0; prefetch A chunks 0,1 of tile t+2
        READ_B(0); READ_B(1); READ_B(2); READ_B(3); READ_A(0);
        if (stg) { load16_g2lds(gA[0] + kk, &lds[sb + lA[0]]);
                   load16_g2lds(gA[1] + kk, &lds[sb + lA[1]]); }
        __builtin_amdgcn_s_barrier();
        __builtin_amdgcn_s_setprio(1);
        MFMA_ROW(0);
        __builtin_amdgcn_s_setprio(0);
        __builtin_amdgcn_s_barrier();
        // phase 1: A row 1; prefetch A chunks 2,3
        READ_A(1);
        if (stg) { load16_g2lds(gA[2] + kk, &lds[sb + lA[2]]);
                   load16_g2lds(gA[3] + kk, &lds[sb + lA[3]]); }
        __builtin_amdgcn_s_barrier();
        __builtin_amdgcn_s_setprio(1);
        MFMA_ROW(1);
        __builtin_amdgcn_s_setprio(0);
        __builtin_amdgcn_s_barrier();
        // phase 2: A row 2; prefetch B chunks 0,1
        READ_A(2);
        if (stg) { load16_g2lds(gB[0] + kk, &lds[sb + lB[0]]);
                   load16_g2lds(gB[1] + kk, &lds[sb + lB[1]]); }
        __builtin_amdgcn_s_barrier();
        __builtin_amdgcn_s_setprio(1);
        MFMA_ROW(2);
        __builtin_amdgcn_s_setprio(0);
        __builtin_amdgcn_s_barrier();
        // phase 3: A row 3 (loop-top barrier of next iter closes the phase)
        READ_A(3);
        __builtin_amdgcn_s_barrier();
        __builtin_amdgcn_s_setprio(1);
        MFMA_ROW(3);
        __builtin_amdgcn_s_setprio(0);

        rd = (rd == 2) ? 0 : rd + 1;
    }

    // ---- final K-tile (t = NT-1): nothing left in flight -> full drain ----
    {
        asm volatile("s_waitcnt vmcnt(0)" ::: "memory");
        __builtin_amdgcn_s_barrier();
        asm volatile("" ::: "memory");
        const uint8_t* Ab = &lds[(uint32_t)rd * BUFB];
        intx8 a[4], b[4];
        READ_B(0); READ_B(1); READ_B(2); READ_B(3);
        READ_A(0); MFMA_ROW(0);
        READ_A(1); MFMA_ROW(1);
        READ_A(2); MFMA_ROW(2);
        READ_A(3); MFMA_ROW(3);
    }

    // ---- epilogue: C/D layout col=lane&15, row=quad*4+reg ----
    const float wsv = wscale[0];
#pragma unroll
    for (int i = 0; i < 4; ++i) {
        const int rbase = m0 + wm + i * 16 + quad * 4;
        float s[4];
#pragma unroll
        for (int r = 0; r < 4; ++r) s[r] = xscale[rbase + r] * wsv;
#pragma unroll
        for (int j = 0; j < 4; ++j) {
            const int col = n0 + wn + j * 16 + row;
#pragma unroll
            for (int r = 0; r < 4; ++r)
                out[(size_t)(rbase + r) * N_DIM + col] = acc[i][j][r] * s[r];
        }
    }
#undef READ_A
#undef READ_B
#undef MFMA_ROW
}

// ---------- launch ----------

extern "C" void kernel_launch(void* const* d_in, const int* in_sizes, int n_in,
                              void* d_out, int out_size, void* d_ws, size_t ws_size,
                              hipStream_t stream) {
    const float* x      = (const float*)d_in[0]; // [8192,4096] fp32
    const float* w      = (const float*)d_in[1]; // [4096,4096] fp32
    const float* wscale = (const float*)d_in[2]; // [1] fp32
    float* out = (float*)d_out;                  // [8192,4096] fp32

    uint8_t* xq  = (uint8_t*)d_ws;
    uint8_t* wqT = xq + (size_t)T_DIM * K_DIM;
    float* xscale = (float*)(wqT + (size_t)N_DIM * K_DIM);

    quant_fused_kernel<<<T_DIM + (N_DIM / 64) * (K_DIM / 64), 256, 0, stream>>>(
        x, w, xq, wqT, xscale);
    gemm_fp8_kernel<<<dim3(N_DIM / 128, T_DIM / 256), 512, 0, stream>>>(
        xq, wqT, xscale, wscale, out);
}

// Round 3
// 395.578 us; speedup vs baseline: 1.0476x; 1.0476x over previous
//
#include <hip/hip_runtime.h>
#include <stdint.h>

#define T_DIM 8192
#define K_DIM 4096
#define N_DIM 4096
#define FP8MAX 448.0f
#define NT     32        // K tiles of 128 B
#define BUFB   32768u    // per-K-tile LDS: A 128x128 B (16K) + B 128x128 B (16K)

typedef __attribute__((ext_vector_type(4))) float floatx4;
typedef __attribute__((ext_vector_type(4))) int   intx4;
typedef __attribute__((ext_vector_type(8))) int   intx8;

// ---------- helpers ----------

__device__ static inline void load16_g2lds(const void* gptr, void* lptr) {
    __builtin_amdgcn_global_load_lds(
        (const __attribute__((address_space(1))) void*)gptr,
        (__attribute__((address_space(3))) void*)lptr,
        16, 0, 0);
}

// pack 4 floats -> 4 fp8 e4m3fn bytes (HW RNE cvt; OCP format on gfx950)
__device__ static inline uint32_t pack4_fp8(float f0, float f1, float f2, float f3) {
    int p = 0;
    p = __builtin_amdgcn_cvt_pk_fp8_f32(f0, f1, p, false); // bytes 0,1
    p = __builtin_amdgcn_cvt_pk_fp8_f32(f2, f3, p, true);  // bytes 2,3
    return (uint32_t)p;
}

// ---------- kernel 1: fused quantization (unchanged from verified version) ----------
__global__ __launch_bounds__(256) void quant_fused_kernel(
    const float* __restrict__ x, const float* __restrict__ w,
    uint8_t* __restrict__ xq, uint8_t* __restrict__ wqT,
    float* __restrict__ xscale)
{
    const int tid = threadIdx.x;
    if (blockIdx.x < T_DIM) {
        const int t = blockIdx.x;
        const int lane = tid & 63;
        const int wave = tid >> 6;
        const float4* xr4 = (const float4*)(x + (size_t)t * K_DIM);

        float4 v[4];
        float m = 0.0f;
#pragma unroll
        for (int e = 0; e < 4; ++e) {
            v[e] = xr4[tid + e * 256];
            m = fmaxf(m, fmaxf(fmaxf(fabsf(v[e].x), fabsf(v[e].y)),
                               fmaxf(fabsf(v[e].z), fabsf(v[e].w))));
        }
#pragma unroll
        for (int off = 32; off > 0; off >>= 1)
            m = fmaxf(m, __shfl_down(m, off, 64));
        __shared__ float red[4];
        if (lane == 0) red[wave] = m;
        __syncthreads();
        float mm = fmaxf(fmaxf(red[0], red[1]), fmaxf(red[2], red[3]));
        float scale = fmaxf(mm / FP8MAX, 1e-12f);
        if (tid == 0) xscale[t] = scale;
        const float inv = 1.0f / scale;

        uint32_t* xqr = (uint32_t*)(xq + (size_t)t * K_DIM);
#pragma unroll
        for (int e = 0; e < 4; ++e) {
            float q0 = fminf(fmaxf(v[e].x * inv, -FP8MAX), FP8MAX);
            float q1 = fminf(fmaxf(v[e].y * inv, -FP8MAX), FP8MAX);
            float q2 = fminf(fmaxf(v[e].z * inv, -FP8MAX), FP8MAX);
            float q3 = fminf(fmaxf(v[e].w * inv, -FP8MAX), FP8MAX);
            xqr[tid + e * 256] = pack4_fp8(q0, q1, q2, q3);
        }
    } else {
        const int b = blockIdx.x - T_DIM;
        const int n0 = (b & 63) * 64;
        const int k0 = (b >> 6) * 64;
        __shared__ uint32_t tile[64][17];

#pragma unroll
        for (int e = 0; e < 4; ++e) {
            int idx = tid + e * 256;
            int r = idx >> 4;
            int c4 = idx & 15;
            float4 v = *(const float4*)(w + (size_t)(k0 + r) * N_DIM + n0 + c4 * 4);
            tile[r][c4] = pack4_fp8(v.x, v.y, v.z, v.w);
        }
        __syncthreads();
        const int kg = tid & 15;
        const int ng = tid >> 4;
        uint32_t in0 = tile[kg * 4 + 0][ng];
        uint32_t in1 = tile[kg * 4 + 1][ng];
        uint32_t in2 = tile[kg * 4 + 2][ng];
        uint32_t in3 = tile[kg * 4 + 3][ng];
#pragma unroll
        for (int i = 0; i < 4; ++i) {
            uint32_t o = ((in0 >> (8 * i)) & 0xFFu)
                       | (((in1 >> (8 * i)) & 0xFFu) << 8)
                       | (((in2 >> (8 * i)) & 0xFFu) << 16)
                       | (((in3 >> (8 * i)) & 0xFFu) << 24);
            *(uint32_t*)(wqT + (size_t)(n0 + ng * 4 + i) * K_DIM + k0 + kg * 4) = o;
        }
    }
}

// ---------- kernel 2: fp8 GEMM, double-buffered minimum pipeline ----------
// 128x128 tile, BK=128B, 4 waves 2x2 (64x64 each), DOUBLE-buffered LDS
// (2x32KB = 64KB -> 2 blocks/CU co-resident, preserving the inter-block
// overlap that carried round-0's 44% MfmaUtil). Per K-tile (minimum T3):
//   issue 8 global_load_lds for tile t+1 -> buf[t+1]   (overlaps compute t)
//   ds_read + 16 MFMA from buf[t]  (setprio(1) around MFMA cluster)
//   __syncthreads()  (vmcnt(0) drain is cheap: loads had full compute to land;
//                     also WAR-fences buf[t+1] reuse)
// One barrier per K-tile vs round-2's eight; no 1-block/CU occupancy cliff.
// LDS XOR-16B swizzle: slot gg = g ^ (row&7), cancelled on read -> identity k.
__global__ __launch_bounds__(256, 3) void gemm_fp8_kernel(
    const uint8_t* __restrict__ xq, const uint8_t* __restrict__ wqT,
    const float* __restrict__ xscale, const float* __restrict__ wscale,
    float* __restrict__ out)
{
    __shared__ __align__(16) uint8_t lds[2 * BUFB]; // 64 KB

    const int tid  = threadIdx.x;
    const int lane = tid & 63;
    const int wave = tid >> 6;
    const int m0 = blockIdx.y * 128;
    const int n0 = blockIdx.x * 128;
    const int wm = (wave >> 1) * 64;
    const int wn = (wave & 1) * 64;
    const int row  = lane & 15;
    const int quad = lane >> 4;

    floatx4 acc[4][4] = {{{0.f,0.f,0.f,0.f}}};

    // staging: 1024 chunks of 16B per matrix per tile; 4 per thread per matrix.
    // LDS slot c=(r,gg) holds global group g = gg ^ (r&7).
    const uint8_t* gA[4];
    const uint8_t* gB[4];
    uint32_t lA[4], lB[4];
#pragma unroll
    for (int p = 0; p < 4; ++p) {
        const int c = tid + p * 256;               // 0..1023 (128 rows x 8 groups)
        const int r = c >> 3, gg = c & 7, g = gg ^ (r & 7);
        gA[p] = xq  + (size_t)(m0 + r) * K_DIM + g * 16;
        gB[p] = wqT + (size_t)(n0 + r) * K_DIM + g * 16;
        lA[p] = (uint32_t)c * 16u;
        lB[p] = 16384u + (uint32_t)c * 16u;
    }

    // frag read offsets (relative to buffer base; swizzle cancels on read)
    int aoff0[4], aoff1[4], boff0[4], boff1[4];
#pragma unroll
    for (int i = 0; i < 4; ++i) {
        const int mr = wm + i * 16 + row;
        const int nr = wn + i * 16 + row;
        aoff0[i] = mr * 128 + (((2 * quad)     ^ (mr & 7)) << 4);
        aoff1[i] = mr * 128 + (((2 * quad + 1) ^ (mr & 7)) << 4);
        boff0[i] = 16384 + nr * 128 + (((2 * quad)     ^ (nr & 7)) << 4);
        boff1[i] = 16384 + nr * 128 + (((2 * quad + 1) ^ (nr & 7)) << 4);
    }

#define READ_A(i) { \
    intx4 lo = *(const intx4*)(Ab + aoff0[i]); \
    intx4 hi = *(const intx4*)(Ab + aoff1[i]); \
    a[i] = __builtin_shufflevector(lo, hi, 0, 1, 2, 3, 4, 5, 6, 7); }
#define READ_B(j) { \
    intx4 lo = *(const intx4*)(Ab + boff0[j]); \
    intx4 hi = *(const intx4*)(Ab + boff1[j]); \
    b[j] = __builtin_shufflevector(lo, hi, 0, 1, 2, 3, 4, 5, 6, 7); }
#define MFMA_ROW(i) \
    acc[i][0] = __builtin_amdgcn_mfma_scale_f32_16x16x128_f8f6f4(a[i], b[0], acc[i][0], 0, 0, 0, 0x7F7F7F7F, 0, 0x7F7F7F7F); \
    acc[i][1] = __builtin_amdgcn_mfma_scale_f32_16x16x128_f8f6f4(a[i], b[1], acc[i][1], 0, 0, 0, 0x7F7F7F7F, 0, 0x7F7F7F7F); \
    acc[i][2] = __builtin_amdgcn_mfma_scale_f32_16x16x128_f8f6f4(a[i], b[2], acc[i][2], 0, 0, 0, 0x7F7F7F7F, 0, 0x7F7F7F7F); \
    acc[i][3] = __builtin_amdgcn_mfma_scale_f32_16x16x128_f8f6f4(a[i], b[3], acc[i][3], 0, 0, 0, 0x7F7F7F7F, 0, 0x7F7F7F7F);

    // prologue: stage tile 0 -> buf0, then one full drain
#pragma unroll
    for (int p = 0; p < 4; ++p) {
        load16_g2lds(gA[p], &lds[lA[p]]);
        load16_g2lds(gB[p], &lds[lB[p]]);
    }
    __syncthreads();

    for (int t = 0; t < NT; ++t) {
        // stage tile t+1 into the other buffer; overlaps this tile's compute.
        // WAR on buf[(t+1)&1] is safe: its readers finished before the
        // __syncthreads() that ended iteration t-1.
        if (t < NT - 1) {
            const uint32_t nb = (uint32_t)((t + 1) & 1) * BUFB;
            const int kk = (t + 1) * 128;
#pragma unroll
            for (int p = 0; p < 4; ++p) {
                load16_g2lds(gA[p] + kk, &lds[nb + lA[p]]);
                load16_g2lds(gB[p] + kk, &lds[nb + lB[p]]);
            }
        }

        const uint8_t* Ab = &lds[(uint32_t)(t & 1) * BUFB];
        intx8 a[4], b[4];
        READ_A(0); READ_A(1); READ_A(2); READ_A(3);
        READ_B(0); READ_B(1); READ_B(2); READ_B(3);
        __builtin_amdgcn_s_setprio(1);
        MFMA_ROW(0); MFMA_ROW(1); MFMA_ROW(2); MFMA_ROW(3);
        __builtin_amdgcn_s_setprio(0);

        // single barrier per K-tile: drains vmcnt(0) (tile t+1 landed during
        // compute) + lgkmcnt, and fences buffer reuse.
        __syncthreads();
    }

    // epilogue: C/D layout col=lane&15, row=quad*4+reg (shape-determined)
    const float wsv = wscale[0];
#pragma unroll
    for (int i = 0; i < 4; ++i) {
        const int rbase = m0 + wm + i * 16 + quad * 4;
        float s[4];
#pragma unroll
        for (int r = 0; r < 4; ++r) s[r] = xscale[rbase + r] * wsv;
#pragma unroll
        for (int j = 0; j < 4; ++j) {
            const int col = n0 + wn + j * 16 + row;
#pragma unroll
            for (int r = 0; r < 4; ++r)
                out[(size_t)(rbase + r) * N_DIM + col] = acc[i][j][r] * s[r];
        }
    }
#undef READ_A
#undef READ_B
#undef MFMA_ROW
}

// ---------- launch ----------

extern "C" void kernel_launch(void* const* d_in, const int* in_sizes, int n_in,
                              void* d_out, int out_size, void* d_ws, size_t ws_size,
                              hipStream_t stream) {
    const float* x      = (const float*)d_in[0]; // [8192,4096] fp32
    const float* w      = (const float*)d_in[1]; // [4096,4096] fp32
    const float* wscale = (const float*)d_in[2]; // [1] fp32
    float* out = (float*)d_out;                  // [8192,4096] fp32

    uint8_t* xq  = (uint8_t*)d_ws;
    uint8_t* wqT = xq + (size_t)T_DIM * K_DIM;
    float* xscale = (float*)(wqT + (size_t)N_DIM * K_DIM);

    quant_fused_kernel<<<T_DIM + (N_DIM / 64) * (K_DIM / 64), 256, 0, stream>>>(
        x, w, xq, wqT, xscale);
    gemm_fp8_kernel<<<dim3(N_DIM / 128, T_DIM / 128), 256, 0, stream>>>(
        xq, wqT, xscale, wscale, out);
}

// Round 4
// 385.384 us; speedup vs baseline: 1.0753x; 1.0265x over previous
//
#include <hip/hip_runtime.h>
#include <stdint.h>

#define T_DIM 8192
#define K_DIM 4096
#define N_DIM 4096
#define FP8MAX 448.0f
#define NT     32        // K tiles of 128 B
#define BUFB   65536u    // per-K-tile LDS: A 256x128 B (32K) + B 256x128 B (32K)

typedef __attribute__((ext_vector_type(4))) float floatx4;
typedef __attribute__((ext_vector_type(4))) int   intx4;
typedef __attribute__((ext_vector_type(8))) int   intx8;

// ---------- helpers ----------

__device__ static inline void load16_g2lds(const void* gptr, void* lptr) {
    __builtin_amdgcn_global_load_lds(
        (const __attribute__((address_space(1))) void*)gptr,
        (__attribute__((address_space(3))) void*)lptr,
        16, 0, 0);
}

// pack 4 floats -> 4 fp8 e4m3fn bytes (HW RNE cvt; OCP format on gfx950)
__device__ static inline uint32_t pack4_fp8(float f0, float f1, float f2, float f3) {
    int p = 0;
    p = __builtin_amdgcn_cvt_pk_fp8_f32(f0, f1, p, false); // bytes 0,1
    p = __builtin_amdgcn_cvt_pk_fp8_f32(f2, f3, p, true);  // bytes 2,3
    return (uint32_t)p;
}

// ---------- kernel 1: fused quantization (unchanged from verified version) ----------
__global__ __launch_bounds__(256) void quant_fused_kernel(
    const float* __restrict__ x, const float* __restrict__ w,
    uint8_t* __restrict__ xq, uint8_t* __restrict__ wqT,
    float* __restrict__ xscale)
{
    const int tid = threadIdx.x;
    if (blockIdx.x < T_DIM) {
        const int t = blockIdx.x;
        const int lane = tid & 63;
        const int wave = tid >> 6;
        const float4* xr4 = (const float4*)(x + (size_t)t * K_DIM);

        float4 v[4];
        float m = 0.0f;
#pragma unroll
        for (int e = 0; e < 4; ++e) {
            v[e] = xr4[tid + e * 256];
            m = fmaxf(m, fmaxf(fmaxf(fabsf(v[e].x), fabsf(v[e].y)),
                               fmaxf(fabsf(v[e].z), fabsf(v[e].w))));
        }
#pragma unroll
        for (int off = 32; off > 0; off >>= 1)
            m = fmaxf(m, __shfl_down(m, off, 64));
        __shared__ float red[4];
        if (lane == 0) red[wave] = m;
        __syncthreads();
        float mm = fmaxf(fmaxf(red[0], red[1]), fmaxf(red[2], red[3]));
        float scale = fmaxf(mm / FP8MAX, 1e-12f);
        if (tid == 0) xscale[t] = scale;
        const float inv = 1.0f / scale;

        uint32_t* xqr = (uint32_t*)(xq + (size_t)t * K_DIM);
#pragma unroll
        for (int e = 0; e < 4; ++e) {
            float q0 = fminf(fmaxf(v[e].x * inv, -FP8MAX), FP8MAX);
            float q1 = fminf(fmaxf(v[e].y * inv, -FP8MAX), FP8MAX);
            float q2 = fminf(fmaxf(v[e].z * inv, -FP8MAX), FP8MAX);
            float q3 = fminf(fmaxf(v[e].w * inv, -FP8MAX), FP8MAX);
            xqr[tid + e * 256] = pack4_fp8(q0, q1, q2, q3);
        }
    } else {
        const int b = blockIdx.x - T_DIM;
        const int n0 = (b & 63) * 64;
        const int k0 = (b >> 6) * 64;
        __shared__ uint32_t tile[64][17];

#pragma unroll
        for (int e = 0; e < 4; ++e) {
            int idx = tid + e * 256;
            int r = idx >> 4;
            int c4 = idx & 15;
            float4 v = *(const float4*)(w + (size_t)(k0 + r) * N_DIM + n0 + c4 * 4);
            tile[r][c4] = pack4_fp8(v.x, v.y, v.z, v.w);
        }
        __syncthreads();
        const int kg = tid & 15;
        const int ng = tid >> 4;
        uint32_t in0 = tile[kg * 4 + 0][ng];
        uint32_t in1 = tile[kg * 4 + 1][ng];
        uint32_t in2 = tile[kg * 4 + 2][ng];
        uint32_t in3 = tile[kg * 4 + 3][ng];
#pragma unroll
        for (int i = 0; i < 4; ++i) {
            uint32_t o = ((in0 >> (8 * i)) & 0xFFu)
                       | (((in1 >> (8 * i)) & 0xFFu) << 8)
                       | (((in2 >> (8 * i)) & 0xFFu) << 16)
                       | (((in3 >> (8 * i)) & 0xFFu) << 24);
            *(uint32_t*)(wqT + (size_t)(n0 + ng * 4 + i) * K_DIM + k0 + kg * 4) = o;
        }
    }
}

// ---------- kernel 2: fp8 GEMM, 256x256 tile for LDS-bandwidth relief ----------
// Theory: MfmaUtil pinned at 44% across 3 structures == LDS-port-bound
// (reads duplicated 2x by wave grid + 4 conflict-cyc per ds_read_b128).
// Fix = raise FLOP per LDS byte: 256x256 block, 8 waves (2M x 4N), wave
// tile 128x64 -> LDS bytes/FLOP falls 1.5x; matrix (2 waves/SIMD x 32
// MFMA x ~35cyc = 2213) now ~= LDS (~2000-2600) per block-K-tile.
// Slot-XOR depends only on row&7 (wm, wn, i*16 all == 0 mod 8), so frag
// addresses = 1 base VGPR + const offsets (i*2048, ^16 for hi half):
// acc 128 + frags 64 VGPR fits the 256 cap of __launch_bounds__(512,2).
// Double-buffered LDS 2x64KB = 128 KB (1 block/CU, 2 waves/SIMD); per
// K-tile: issue 8 DMA for t+1, compute t, one __syncthreads.
__global__ __launch_bounds__(512, 2) void gemm_fp8_kernel(
    const uint8_t* __restrict__ xq, const uint8_t* __restrict__ wqT,
    const float* __restrict__ xscale, const float* __restrict__ wscale,
    float* __restrict__ out)
{
    __shared__ __align__(16) uint8_t lds[2 * BUFB]; // 128 KB

    const int tid  = threadIdx.x;   // 0..511
    const int lane = tid & 63;
    const int wave = tid >> 6;      // 0..7
    const int m0 = blockIdx.y * 256;
    const int n0 = blockIdx.x * 256;
    const int wm = (wave >> 2) * 128; // 0,128
    const int wn = (wave & 3) * 64;   // 0,64,128,192
    const int row  = lane & 15;
    const int quad = lane >> 4;

    floatx4 acc[8][4] = {{{0.f,0.f,0.f,0.f}}};

    // ---- staging bases: 2048 cells of 16B per matrix, 4 per thread.
    // cell c = tid + p*512: r = c>>3, gg = c&7, g = gg ^ (r&7).
    // p-stride: r += 64 (r&7 invariant), so global stride = 64*K_DIM,
    // LDS stride = 8192. One base pointer each.
    const int r0 = tid >> 3;                 // 0..63
    const int g0 = (tid & 7) ^ (r0 & 7);
    const uint8_t* gAb = xq  + (size_t)(m0 + r0) * K_DIM + g0 * 16;
    const uint8_t* gBb = wqT + (size_t)(n0 + r0) * K_DIM + g0 * 16;
    const uint32_t lA0 = (uint32_t)tid * 16u;
    const uint32_t lB0 = 32768u + (uint32_t)tid * 16u;

    // ---- fragment bases (swizzle slot depends only on row&7) ----
    const int slot = ((2 * quad) ^ (row & 7)) << 4;
    const int abase = (wm + row) * 128 + slot;             // + i*2048, ^16 for hi
    const int bbase = 32768 + (wn + row) * 128 + slot;     // + j*2048, ^16 for hi

#define STAGE(kk, nb) do { \
    _Pragma("unroll") \
    for (int p = 0; p < 4; ++p) { \
        load16_g2lds(gAb + (size_t)p * 64 * K_DIM + (kk), &lds[(nb) + lA0 + p * 8192u]); \
        load16_g2lds(gBb + (size_t)p * 64 * K_DIM + (kk), &lds[(nb) + lB0 + p * 8192u]); \
    } } while (0)

#define READ_A(d, i) { \
    intx4 lo = *(const intx4*)(Ab + abase + (i) * 2048); \
    intx4 hi = *(const intx4*)(Ab + (abase ^ 16) + (i) * 2048); \
    a[d] = __builtin_shufflevector(lo, hi, 0, 1, 2, 3, 4, 5, 6, 7); }
#define READ_B(j) { \
    intx4 lo = *(const intx4*)(Ab + bbase + (j) * 2048); \
    intx4 hi = *(const intx4*)(Ab + (bbase ^ 16) + (j) * 2048); \
    b[j] = __builtin_shufflevector(lo, hi, 0, 1, 2, 3, 4, 5, 6, 7); }
#define MFMA4(i, d) \
    acc[i][0] = __builtin_amdgcn_mfma_scale_f32_16x16x128_f8f6f4(a[d], b[0], acc[i][0], 0, 0, 0, 0x7F7F7F7F, 0, 0x7F7F7F7F); \
    acc[i][1] = __builtin_amdgcn_mfma_scale_f32_16x16x128_f8f6f4(a[d], b[1], acc[i][1], 0, 0, 0, 0x7F7F7F7F, 0, 0x7F7F7F7F); \
    acc[i][2] = __builtin_amdgcn_mfma_scale_f32_16x16x128_f8f6f4(a[d], b[2], acc[i][2], 0, 0, 0, 0x7F7F7F7F, 0, 0x7F7F7F7F); \
    acc[i][3] = __builtin_amdgcn_mfma_scale_f32_16x16x128_f8f6f4(a[d], b[3], acc[i][3], 0, 0, 0, 0x7F7F7F7F, 0, 0x7F7F7F7F);

    // ---- prologue: stage tile 0 -> buf0, full drain once ----
    STAGE(0, 0u);
    __syncthreads();

    for (int t = 0; t < NT; ++t) {
        // stage tile t+1 (overlaps this tile's compute; WAR safe: buf's
        // readers finished before the __syncthreads ending iteration t-1)
        if (t < NT - 1) STAGE((t + 1) * 128, (uint32_t)((t + 1) & 1) * BUFB);

        const uint8_t* Ab = &lds[(uint32_t)(t & 1) * BUFB];
        intx8 a[4], b[4];
        READ_B(0); READ_B(1); READ_B(2); READ_B(3);
        // half 0: A frags 0..3
        READ_A(0, 0); READ_A(1, 1); READ_A(2, 2); READ_A(3, 3);
        __builtin_amdgcn_s_setprio(1);
        MFMA4(0, 0); MFMA4(1, 1); MFMA4(2, 2); MFMA4(3, 3);
        __builtin_amdgcn_s_setprio(0);
        // half 1: A frags 4..7 (a[] reused -> caps live registers)
        READ_A(0, 4); READ_A(1, 5); READ_A(2, 6); READ_A(3, 7);
        __builtin_amdgcn_s_setprio(1);
        MFMA4(4, 0); MFMA4(5, 1); MFMA4(6, 2); MFMA4(7, 3);
        __builtin_amdgcn_s_setprio(0);

        // single barrier per K-tile: drains vmcnt (t+1 landed during compute)
        // and fences buffer reuse.
        __syncthreads();
    }

    // ---- epilogue: C/D layout col=lane&15, row=quad*4+reg ----
    const float wsv = wscale[0];
#pragma unroll
    for (int i = 0; i < 8; ++i) {
        const int rbase = m0 + wm + i * 16 + quad * 4;
        float s[4];
#pragma unroll
        for (int r = 0; r < 4; ++r) s[r] = xscale[rbase + r] * wsv;
#pragma unroll
        for (int j = 0; j < 4; ++j) {
            const int col = n0 + wn + j * 16 + row;
#pragma unroll
            for (int r = 0; r < 4; ++r)
                out[(size_t)(rbase + r) * N_DIM + col] = acc[i][j][r] * s[r];
        }
    }
#undef STAGE
#undef READ_A
#undef READ_B
#undef MFMA4
}

// ---------- launch ----------

extern "C" void kernel_launch(void* const* d_in, const int* in_sizes, int n_in,
                              void* d_out, int out_size, void* d_ws, size_t ws_size,
                              hipStream_t stream) {
    const float* x      = (const float*)d_in[0]; // [8192,4096] fp32
    const float* w      = (const float*)d_in[1]; // [4096,4096] fp32
    const float* wscale = (const float*)d_in[2]; // [1] fp32
    float* out = (float*)d_out;                  // [8192,4096] fp32

    uint8_t* xq  = (uint8_t*)d_ws;
    uint8_t* wqT = xq + (size_t)T_DIM * K_DIM;
    float* xscale = (float*)(wqT + (size_t)N_DIM * K_DIM);

    quant_fused_kernel<<<T_DIM + (N_DIM / 64) * (K_DIM / 64), 256, 0, stream>>>(
        x, w, xq, wqT, xscale);
    gemm_fp8_kernel<<<dim3(N_DIM / 256, T_DIM / 256), 512, 0, stream>>>(
        xq, wqT, xscale, wscale, out);
}